// Round 7
// baseline (214.198 us; speedup 1.0000x reference)
//
#include <hip/hip_runtime.h>

// STGraphConstructor: adj[b] = tanh(relu(A_b A_b^T) + I), A_b = [5096 x 64] fp32.
// R7: fill-mimicking store stream.
//  - Evidence: fill kernel = 6.8 TB/s at 3.4 waves/CU with per-wave sequential 1KB
//    store instructions; all tile kernels = ~3.3 TB/s from thousands of short
//    interleaved row-fragments. R1 (fewest resident blocks) is best at 122.7.
//  - Tile = 16 rows x 1024 cols computed into 64KB LDS (XOR-swizzled), then each
//    wave streams 4 rows as 4 back-to-back 1KB wave-instructions per row (full
//    128B lines, 4KB sequential per row). 2 blocks/CU (LDS-bound), 8 waves/CU.
//  - Chunk-fastest XCD-pinned order: same XCD continues the same 16 rows across
//    chunks -> DRAM page continuation.
//  - prep kernel (fp32 -> hi/lo bf16) + 3-product split-bf16 MFMA unchanged.

#define NSP 5000
#define NTM 96
#define MM  5096
#define DD  64
#define RB  16     // rows per block
#define CB  1024   // cols per block
#define NBAND 319  // ceil(5096/16)
#define NCH 5      // 5*1024 = 5120 >= 5096
#define TPB 1595   // NBAND*NCH tiles per batch

typedef __attribute__((ext_vector_type(8))) short short8;
typedef __attribute__((ext_vector_type(8))) unsigned short ushort8;
typedef __attribute__((ext_vector_type(4))) float f32x4;

__device__ __forceinline__ unsigned short bf16_rn(float x) {
  unsigned u = __float_as_uint(x);
  u += 0x7FFFu + ((u >> 16) & 1u);
  return (unsigned short)(u >> 16);
}
__device__ __forceinline__ float bf16_f32(unsigned short s) {
  return __uint_as_float(((unsigned)s) << 16);
}

// ---- prep: convert concat(sp,tm) [B][MM][DD] fp32 -> hi/lo bf16 panels ----
__global__ __launch_bounds__(256) void stg_prep_kernel(
    const float* __restrict__ sp, const float* __restrict__ tm,
    unsigned short* __restrict__ wsh, unsigned short* __restrict__ wsl) {
  const int tid = blockIdx.x * 256 + threadIdx.x;
  const int flat = tid * 8;
  const int b = flat / (MM * DD);
  const int rem = flat - b * (MM * DD);
  const int m = rem / DD;
  const int d = rem - m * DD;
  const float* src = (m < NSP)
      ? sp + ((size_t)b * NSP + m) * DD + d
      : tm + ((size_t)b * NTM + (m - NSP)) * DD + d;
  const float4* s4 = reinterpret_cast<const float4*>(src);
  float f[8];
  {
    float4 v0 = s4[0], v1 = s4[1];
    f[0]=v0.x; f[1]=v0.y; f[2]=v0.z; f[3]=v0.w;
    f[4]=v1.x; f[5]=v1.y; f[6]=v1.z; f[7]=v1.w;
  }
  ushort8 H, L;
  #pragma unroll
  for (int i = 0; i < 8; ++i) {
    const unsigned short hi = bf16_rn(f[i]);
    H[i] = hi;
    L[i] = bf16_rn(f[i] - bf16_f32(hi));
  }
  *reinterpret_cast<ushort8*>(wsh + flat) = H;
  *reinterpret_cast<ushort8*>(wsl + flat) = L;
}

// ---- main: 16x1024 LDS-staged tile, fill-order streaming epilogue ----
__global__ __launch_bounds__(256) void stg_adj_kernel(
    const unsigned short* __restrict__ wsh,
    const unsigned short* __restrict__ wsl,
    float* __restrict__ out) {
  __shared__ float lds[RB * CB];   // 64 KB -> 2 blocks/CU

  // XCD pinning: x = wid%8 -> XCD; batch b owns residues {2b,2b+1}.
  const int wid = blockIdx.x;
  const int x = wid & 7;
  const int b = x >> 1;
  const int tt = (wid >> 3) * 2 + (x & 1);   // 0..1595
  if (tt >= TPB) return;
  const int band = tt / NCH;                 // 0..318
  const int chunk = tt - band * NCH;         // 0..4

  const int t = threadIdx.x;
  const int lane = t & 63;
  const int wave = t >> 6;
  const int lr = lane & 15;
  const int lg = lane >> 4;

  const size_t pb = (size_t)b * MM * DD;
  const char* Xh = reinterpret_cast<const char*>(wsh + pb);
  const char* Xl = reinterpret_cast<const char*>(wsl + pb);

  // A-frags: the block's 16 rows, K=64 in regs (verified operand scheme)
  int ra = band * RB + lr; ra = ra < MM ? ra : MM - 1;
  const unsigned offa = (unsigned)ra * 128u + (unsigned)lg * 16u;
  const short8 ah0 = *reinterpret_cast<const short8*>(Xh + offa);
  const short8 ah1 = *reinterpret_cast<const short8*>(Xh + offa + 64u);
  const short8 al0 = *reinterpret_cast<const short8*>(Xl + offa);
  const short8 al1 = *reinterpret_cast<const short8*>(Xl + offa + 64u);

  const int cw = chunk * CB + wave * 256;    // this wave's 256-col strip
  const int grm = band * RB + lr;            // lane's output row (for eye)

  // software-pipelined loop over 16 col-tiles of 16
  short8 bh0, bh1, bl0, bl1, nh0, nh1, nl0, nl1;
  {
    int rb_ = cw + lr; rb_ = rb_ < MM ? rb_ : MM - 1;
    const unsigned offb = (unsigned)rb_ * 128u + (unsigned)lg * 16u;
    bh0 = *reinterpret_cast<const short8*>(Xh + offb);
    bh1 = *reinterpret_cast<const short8*>(Xh + offb + 64u);
    bl0 = *reinterpret_cast<const short8*>(Xl + offb);
    bl1 = *reinterpret_cast<const short8*>(Xl + offb + 64u);
  }
  #pragma unroll 4
  for (int nt = 0; nt < 16; ++nt) {
    if (nt < 15) {
      int rb_ = cw + (nt + 1) * 16 + lr; rb_ = rb_ < MM ? rb_ : MM - 1;
      const unsigned offb = (unsigned)rb_ * 128u + (unsigned)lg * 16u;
      nh0 = *reinterpret_cast<const short8*>(Xh + offb);
      nh1 = *reinterpret_cast<const short8*>(Xh + offb + 64u);
      nl0 = *reinterpret_cast<const short8*>(Xl + offb);
      nl1 = *reinterpret_cast<const short8*>(Xl + offb + 64u);
    }
    f32x4 acc = (f32x4){0.f, 0.f, 0.f, 0.f};
    acc = __builtin_amdgcn_mfma_f32_16x16x32_bf16(bh0, ah0, acc, 0, 0, 0);
    acc = __builtin_amdgcn_mfma_f32_16x16x32_bf16(bh1, ah1, acc, 0, 0, 0);
    acc = __builtin_amdgcn_mfma_f32_16x16x32_bf16(bh0, al0, acc, 0, 0, 0);
    acc = __builtin_amdgcn_mfma_f32_16x16x32_bf16(bh1, al1, acc, 0, 0, 0);
    acc = __builtin_amdgcn_mfma_f32_16x16x32_bf16(bl0, ah0, acc, 0, 0, 0);
    acc = __builtin_amdgcn_mfma_f32_16x16x32_bf16(bl1, ah1, acc, 0, 0, 0);

    // tanh(relu(x)+eye) -> swizzled LDS (lane holds row lr, 4 consecutive cols)
    const int gc0 = cw + nt * 16 + lg * 4;
    f32x4 v;
    #pragma unroll
    for (int q = 0; q < 4; ++q) {
      float xv = fmaxf(acc[q], 0.f);
      xv += (grm == gc0 + q) ? 1.f : 0.f;
      const float e = __builtin_amdgcn_exp2f(xv * 2.8853900817779268f);
      v[q] = 1.f - 2.f * __builtin_amdgcn_rcpf(e + 1.f);
    }
    // granule index (16B units) within row, XOR-swizzled by row low bits
    const unsigned g = ((unsigned)(wave * 64 + nt * 4 + lg)) ^ ((unsigned)lr & 7u);
    *reinterpret_cast<f32x4*>(reinterpret_cast<char*>(lds) + (unsigned)lr * 4096u + g * 16u) = v;

    bh0 = nh0; bh1 = nh1; bl0 = nl0; bl1 = nl1;
  }
  __syncthreads();

  // ---- fill-order streaming epilogue: wave w streams rows 4w..4w+3,
  //      each row as 4 back-to-back 1KB contiguous wave-instructions ----
  const int clim = (chunk == NCH - 1) ? (MM - chunk * CB) : CB;   // 1000 or 1024
  const size_t cbase = (size_t)b * MM * MM + (size_t)chunk * CB;
  #pragma unroll
  for (int rr = 0; rr < 4; ++rr) {
    const int lrow = wave * 4 + rr;
    const int grow = band * RB + lrow;
    if (grow < MM) {
      float* rowp = out + cbase + (size_t)grow * MM;
      #pragma unroll
      for (int k = 0; k < 4; ++k) {
        const int col = k * 256 + lane * 4;
        if (col < clim) {
          const unsigned g = ((unsigned)(k * 64 + lane)) ^ ((unsigned)lrow & 7u);
          const f32x4 v = *reinterpret_cast<const f32x4*>(
              reinterpret_cast<const char*>(lds) + (unsigned)lrow * 4096u + g * 16u);
          *reinterpret_cast<f32x4*>(rowp + col) = v;
        }
      }
    }
  }
}

extern "C" void kernel_launch(void* const* d_in, const int* in_sizes, int n_in,
                              void* d_out, int out_size, void* d_ws, size_t ws_size,
                              hipStream_t stream) {
  const float* sp = (const float*)d_in[0];
  const float* tm = (const float*)d_in[1];
  float* out = (float*)d_out;
  const int B = in_sizes[0] / (NSP * DD);   // = 4
  unsigned short* wsh = (unsigned short*)d_ws;
  unsigned short* wsl = wsh + (size_t)B * MM * DD;

  const int prep_threads = B * MM * DD / 8;
  stg_prep_kernel<<<dim3(prep_threads / 256), dim3(256), 0, stream>>>(sp, tm, wsh, wsl);

  // 6384 = 798*8 blocks; 4 tail blocks (tt==1595) exit immediately
  stg_adj_kernel<<<dim3(798 * 8), dim3(256), 0, stream>>>(wsh, wsl, out);
}

// Round 8
// 109.242 us; speedup vs baseline: 1.9608x; 1.9608x over previous
//
#include <hip/hip_runtime.h>

// STGraphConstructor: adj[b] = tanh(relu(A_b A_b^T) + I), A_b = [5096 x 64] fp32.
// R8: R1's proven skeleton + every individually-validated improvement.
//  - Ledger: R1 (LDS-staged inputs, 2 blk/CU) = 122.7 beats R3/R4 (L2-direct
//    divergent fragment reads) = 136 despite doing MORE work. Store-pattern
//    variants (R2,R5,R6,R7) all lose. => optimize the in-block read path, keep
//    R1's residency and dispatch order untouched.
//  - prep kernel pre-converts fp32 -> hi/lo bf16 once (validated, ~4us, FETCH 20MB).
//  - main: stage hi/lo panels into 64KB LDS with COALESCED bf16x8 loads (1KB/wave
//    -instr), XOR-swizzled rows; fragments from LDS; swapped-operand MFMA
//    (lane = output row, 4 consecutive cols) -> 16 float4 burst stores.
//  - grid(40,40,4) exactly like R1; __launch_bounds__(256,2); 2 blocks/CU.

#define NSP 5000
#define NTM 96
#define MM  5096
#define DD  64
#define BT  128
#define NTILE 40   // ceil(5096/128)

typedef __attribute__((ext_vector_type(8))) short short8;
typedef __attribute__((ext_vector_type(8))) unsigned short ushort8;
typedef __attribute__((ext_vector_type(4))) float f32x4;

__device__ __forceinline__ unsigned short bf16_rn(float x) {
  unsigned u = __float_as_uint(x);
  u += 0x7FFFu + ((u >> 16) & 1u);
  return (unsigned short)(u >> 16);
}
__device__ __forceinline__ float bf16_f32(unsigned short s) {
  return __uint_as_float(((unsigned)s) << 16);
}

// ---- prep: convert concat(sp,tm) [B][MM][DD] fp32 -> hi/lo bf16 panels ----
__global__ __launch_bounds__(256) void stg_prep_kernel(
    const float* __restrict__ sp, const float* __restrict__ tm,
    unsigned short* __restrict__ wsh, unsigned short* __restrict__ wsl) {
  const int tid = blockIdx.x * 256 + threadIdx.x;
  const int flat = tid * 8;
  const int b = flat / (MM * DD);
  const int rem = flat - b * (MM * DD);
  const int m = rem / DD;
  const int d = rem - m * DD;
  const float* src = (m < NSP)
      ? sp + ((size_t)b * NSP + m) * DD + d
      : tm + ((size_t)b * NTM + (m - NSP)) * DD + d;
  const float4* s4 = reinterpret_cast<const float4*>(src);
  float f[8];
  {
    float4 v0 = s4[0], v1 = s4[1];
    f[0]=v0.x; f[1]=v0.y; f[2]=v0.z; f[3]=v0.w;
    f[4]=v1.x; f[5]=v1.y; f[6]=v1.z; f[7]=v1.w;
  }
  ushort8 H, L;
  #pragma unroll
  for (int i = 0; i < 8; ++i) {
    const unsigned short hi = bf16_rn(f[i]);
    H[i] = hi;
    L[i] = bf16_rn(f[i] - bf16_f32(hi));
  }
  *reinterpret_cast<ushort8*>(wsh + flat) = H;
  *reinterpret_cast<ushort8*>(wsl + flat) = L;
}

// ---- main: 128x128 tile, LDS-staged pre-converted panels ----
__global__ __launch_bounds__(256, 2) void stg_adj_kernel(
    const unsigned short* __restrict__ wsh,
    const unsigned short* __restrict__ wsl,
    float* __restrict__ out) {
  __shared__ unsigned char lds[65536];   // 4 x 16KB: RH, RL, CH, CL
  const int bi = blockIdx.x;
  const int bj = blockIdx.y;
  const int b  = blockIdx.z;
  const int t  = threadIdx.x;

  const size_t pb = (size_t)b * MM * DD;

  // ---- staging: 4 components x 4 granules/thread, coalesced 16B loads ----
  #pragma unroll
  for (int comp = 0; comp < 4; ++comp) {
    const int tbase = (comp < 2 ? bi : bj) * BT;
    const unsigned short* src = ((comp & 1) ? wsl : wsh) + pb;
    unsigned char* dst = lds + comp * 16384;
    #pragma unroll
    for (int k = 0; k < 4; ++k) {
      const int G = t + k * 256;          // granule 0..1023
      const int row = G >> 3;             // 0..127
      const int g = G & 7;                // 16B granule within row
      int grow = tbase + row; grow = grow < MM ? grow : MM - 1;
      const ushort8 v = *reinterpret_cast<const ushort8*>(src + (size_t)grow * DD + g * 8);
      *reinterpret_cast<ushort8*>(dst + row * 128 + ((g ^ (row & 7)) << 4)) = v;
    }
  }
  __syncthreads();

  // ---- compute: each wave owns a 64x64 quadrant = 4x4 MFMA tiles ----
  const int lane = t & 63;
  const int wave = t >> 6;
  const int wr = (wave >> 1) << 6;
  const int wc = (wave & 1) << 6;
  const int lr = lane & 15;
  const int lg = lane >> 4;

  f32x4 acc[4][4];
  #pragma unroll
  for (int m = 0; m < 4; ++m)
    #pragma unroll
    for (int n = 0; n < 4; ++n)
      acc[m][n] = (f32x4){0.f, 0.f, 0.f, 0.f};

  #pragma unroll
  for (int ks = 0; ks < 2; ++ks) {
    short8 ah[4], al[4], ch[4], cl[4];
    #pragma unroll
    for (int m = 0; m < 4; ++m) {
      const int ra = wr + m * 16 + lr;    // local row in row-panel
      const unsigned ga = (unsigned)((lg + ks * 4) ^ (ra & 7)) << 4;
      ah[m] = *reinterpret_cast<short8*>(lds +         ra * 128 + ga);
      al[m] = *reinterpret_cast<short8*>(lds + 16384 + ra * 128 + ga);
      const int rc = wc + m * 16 + lr;    // local row in col-panel
      const unsigned gc_ = (unsigned)((lg + ks * 4) ^ (rc & 7)) << 4;
      ch[m] = *reinterpret_cast<short8*>(lds + 32768 + rc * 128 + gc_);
      cl[m] = *reinterpret_cast<short8*>(lds + 49152 + rc * 128 + gc_);
    }
    // swapped operands (R4-verified): lane holds row gr0+m*16+lr, cols gc0+n*16+lg*4+q
    #pragma unroll
    for (int m = 0; m < 4; ++m) {
      #pragma unroll
      for (int n = 0; n < 4; ++n) {
        acc[m][n] = __builtin_amdgcn_mfma_f32_16x16x32_bf16(ch[n], ah[m], acc[m][n], 0, 0, 0);
        acc[m][n] = __builtin_amdgcn_mfma_f32_16x16x32_bf16(ch[n], al[m], acc[m][n], 0, 0, 0);
        acc[m][n] = __builtin_amdgcn_mfma_f32_16x16x32_bf16(cl[n], ah[m], acc[m][n], 0, 0, 0);
      }
    }
  }

  // ---- epilogue: tanh(relu(x)+eye), direct float4 burst stores ----
  const size_t cbase = (size_t)b * MM * MM;
  const int gr0 = bi * BT + wr;
  const int gc0 = bj * BT + wc;
  #pragma unroll
  for (int m = 0; m < 4; ++m) {
    const int gr = gr0 + m * 16 + lr;
    if (gr < MM) {
      float* rowp = out + cbase + (size_t)gr * MM;
      #pragma unroll
      for (int n = 0; n < 4; ++n) {
        const int gc = gc0 + n * 16 + lg * 4;
        if (gc < MM) {   // gc, MM multiples of 4 => whole float4 in bounds
          f32x4 v;
          #pragma unroll
          for (int q = 0; q < 4; ++q) {
            float xv = fmaxf(acc[m][n][q], 0.f);
            xv += (gr == gc + q) ? 1.f : 0.f;
            const float e = __builtin_amdgcn_exp2f(xv * 2.8853900817779268f);
            v[q] = 1.f - 2.f * __builtin_amdgcn_rcpf(e + 1.f);
          }
          *reinterpret_cast<f32x4*>(rowp + gc) = v;
        }
      }
    }
  }
}

extern "C" void kernel_launch(void* const* d_in, const int* in_sizes, int n_in,
                              void* d_out, int out_size, void* d_ws, size_t ws_size,
                              hipStream_t stream) {
  const float* sp = (const float*)d_in[0];
  const float* tm = (const float*)d_in[1];
  float* out = (float*)d_out;
  const int B = in_sizes[0] / (NSP * DD);   // = 4
  unsigned short* wsh = (unsigned short*)d_ws;
  unsigned short* wsl = wsh + (size_t)B * MM * DD;

  const int prep_threads = B * MM * DD / 8;
  stg_prep_kernel<<<dim3(prep_threads / 256), dim3(256), 0, stream>>>(sp, tm, wsh, wsl);

  dim3 grid(NTILE, NTILE, B);
  stg_adj_kernel<<<grid, dim3(256), 0, stream>>>(wsh, wsl, out);
}